// Round 2
// baseline (875.284 us; speedup 1.0000x reference)
//
#include <hip/hip_runtime.h>
#include <hip/hip_bf16.h>

typedef __hip_bfloat16 bf16;
typedef long long i64t;

__device__ __forceinline__ float b2f(bf16 x) { return __bfloat162float(x); }
__device__ __forceinline__ bf16 f2b(float x) { return __float2bfloat16(x); }

// runtime-dtype accessors: isbf/is64 are wave-uniform device flags
__device__ __forceinline__ float loadF(const void* p, int isbf, long long i) {
    return isbf ? b2f(((const bf16*)p)[i]) : ((const float*)p)[i];
}
__device__ __forceinline__ int loadI(const void* p, int is64, long long i) {
    return is64 ? (int)((const i64t*)p)[i] : ((const int*)p)[i];
}
__device__ __forceinline__ void storeO(void* p, int isbf, long long i, float v) {
    if (isbf) ((bf16*)p)[i] = f2b(v);
    else ((float*)p)[i] = v;
}

#define SELU_ALPHA 1.6732632423543772f
#define SELU_SCALE 1.0507009873554805f
__device__ __forceinline__ float selu_f(float x) {
    return SELU_SCALE * (x > 0.f ? x : SELU_ALPHA * (expf(x) - 1.f));
}

__device__ __forceinline__ void atomAddF(float* p, float v) { unsafeAtomicAdd(p, v); }

// red[] layout (floats): [0,1024) sty  [1024,1280) out_adj  [1280,1536) ss
// [1536,1552) ca  [1552,1568) colsum  [1568] two_m ; flags (2 ints) at [2048]
#define RED_STY 0
#define RED_OADJ 1024
#define RED_SS 1280
#define RED_CA 1536
#define RED_CS 1552
#define RED_2M 1568

// ---- dtype probe: flags[0]=floats-are-bf16, flags[1]=indices-are-int64 ----
__global__ void k_probe(const void* W1, const void* eidx, int* flags) {
    __shared__ int sc[2];
    if (threadIdx.x == 0) { sc[0] = 0; sc[1] = 0; }
    __syncthreads();
    // W1 has 4096 float elements; scan first 2048 32-bit words (safe both ways).
    // If bf16: low half of each word is a real bf16 -> exponent field plausible.
    // If fp32: low half is mantissa bits -> exponent field ~uniform (19% hit).
    const unsigned* w = (const unsigned*)W1;
    int c0 = 0;
    for (int i = threadIdx.x; i < 2048; i += 256) {
        unsigned lo = w[i] & 0xFFFFu;
        unsigned e = (lo >> 7) & 0xFFu;
        if (e == 0u || (e >= 0x60u && e <= 0x8Fu)) c0++;
    }
    // edge_index: if int64, odd 32-bit words are high halves == 0 (values < 2^31)
    const unsigned* iw = (const unsigned*)eidx;
    int c1 = 0;
    for (int i = threadIdx.x; i < 2048; i += 256)
        if (iw[2 * i + 1] == 0u) c1++;
    atomicAdd(&sc[0], c0);
    atomicAdd(&sc[1], c1);
    __syncthreads();
    if (threadIdx.x == 0) {
        flags[0] = sc[0] > 1200 ? 1 : 0;
        flags[1] = sc[1] > 1024 ? 1 : 0;
    }
}

// ---- degrees: deg[dst]+=w, dsrc[src]+=w, two_m+=w ----
__global__ void k_degrees(const void* __restrict__ eidx, const void* __restrict__ ew,
                          const int* __restrict__ flags, float* __restrict__ deg,
                          float* __restrict__ dsrc, float* __restrict__ two_m, int E) {
    int g = blockIdx.x * 256 + threadIdx.x;
    int fb = flags[0], fi = flags[1];
    float w = 0.f;
    if (g < E) {
        w = loadF(ew, fb, g);
        atomAddF(&deg[loadI(eidx, fi, (long long)E + g)], w);
        atomAddF(&dsrc[loadI(eidx, fi, g)], w);
    }
    for (int m = 32; m; m >>= 1) w += __shfl_down(w, m, 64);
    __shared__ float part[4];
    if ((threadIdx.x & 63) == 0) part[threadIdx.x >> 6] = w;
    __syncthreads();
    if (threadIdx.x == 0) atomAddF(two_m, part[0] + part[1] + part[2] + part[3]);
}

// ---- deg -> dinv (in place), deg includes +1 self loop ----
__global__ void k_dinv(float* deg, int n) {
    int i = blockIdx.x * 256 + threadIdx.x;
    if (i < n) deg[i] = rsqrtf(deg[i] + 1.f);
}

// ---- per-edge norm coefficient ----
__global__ void k_coef(const void* __restrict__ eidx, const void* __restrict__ ew,
                       const int* __restrict__ flags, const float* __restrict__ dinv,
                       float* __restrict__ coef, int E) {
    int e = blockIdx.x * 256 + threadIdx.x;
    if (e >= E) return;
    int fb = flags[0], fi = flags[1];
    int s = loadI(eidx, fi, e), d = loadI(eidx, fi, (long long)E + e);
    coef[e] = dinv[s] * loadF(ew, fb, e) * dinv[d];
}

// ---- out[N,64] = in[N,64] @ W[64,64]; in dtype per in_tag (0=f32, 1=flagged) ----
__global__ void k_gemm64(const void* __restrict__ in, int in_tag,
                         const void* __restrict__ W, const int* __restrict__ flags,
                         float* __restrict__ out, int n) {
    __shared__ float Wl[4096];
    __shared__ float Rl[256];
    int t = threadIdx.x;
    int fb = flags[0];
    int inbf = in_tag ? fb : 0;
    for (int idx = t; idx < 4096; idx += 256) Wl[idx] = loadF(W, fb, idx);
    int r0 = blockIdx.x * 4;
    {
        int rl = t >> 6, k = t & 63;
        int r = r0 + rl;
        Rl[t] = (r < n) ? loadF(in, inbf, (long long)r * 64 + k) : 0.f;
    }
    __syncthreads();
    int rl = t >> 6, c = t & 63;
    float acc = 0.f;
#pragma unroll
    for (int k = 0; k < 64; k++) acc += Rl[rl * 64 + k] * Wl[k * 64 + c];
    int r = r0 + rl;
    if (r < n) out[r * 64 + c] = acc;
}

// ---- edge propagation: agg[dst,f] += coef[e] * hin[src,f]; wave = edge ----
__global__ void k_prop(const void* __restrict__ eidx, const int* __restrict__ flags,
                       const float* __restrict__ coef, const float* __restrict__ hin,
                       float* __restrict__ agg, int E, int total) {
    int g = blockIdx.x * 256 + threadIdx.x;
    if (g >= total) return;
    int fi = flags[1];
    int e = g >> 6, f = g & 63;
    int s = loadI(eidx, fi, e), d = loadI(eidx, fi, (long long)E + e);
    atomAddF(&agg[(long long)d * 64 + f], coef[e] * hin[(long long)s * 64 + f]);
}

// ---- add self loop + bias, SELU, in place on agg ----
__global__ void k_finish(float* __restrict__ agg, const float* __restrict__ hlin,
                         const float* __restrict__ dinv, const void* __restrict__ b,
                         const int* __restrict__ flags, int total) {
    int g = blockIdx.x * 256 + threadIdx.x;
    if (g >= total) return;
    int fb = flags[0];
    int ni = g >> 6, f = g & 63;
    float di = dinv[ni];
    float v = agg[g] + di * di * hlin[g] + loadF(b, fb, f);
    agg[g] = selu_f(v);
}

// ---- logits + softmax -> sbuf (fp32) + out (flagged dtype) ----
__global__ void k_softmax(const float* __restrict__ y, const void* __restrict__ Wp,
                          const void* __restrict__ bp, const int* __restrict__ flags,
                          float* __restrict__ sbuf, void* __restrict__ sout, int n) {
    __shared__ float Wl[1024];
    __shared__ float bl[16];
    __shared__ float yl[1024];
    int t = threadIdx.x;
    int fb = flags[0];
    for (int idx = t; idx < 1024; idx += 256) Wl[idx] = loadF(Wp, fb, idx);
    if (t < 16) bl[t] = loadF(bp, fb, t);
    int g0 = blockIdx.x * 16;
    for (int idx = t; idx < 1024; idx += 256) {
        int nl = idx >> 6, f = idx & 63;
        int g = g0 + nl;
        yl[idx] = (g < n) ? y[(long long)g * 64 + f] : 0.f;
    }
    __syncthreads();
    int nl = t >> 4, k = t & 15;
    int g = g0 + nl;
    float logit = bl[k];
#pragma unroll
    for (int jj = 0; jj < 64; jj++) logit += yl[nl * 64 + jj] * Wl[jj * 16 + k];
    float mx = logit;
    for (int m = 8; m; m >>= 1) mx = fmaxf(mx, __shfl_xor(mx, m, 16));
    float e = expf(logit - mx);
    float sum = e;
    for (int m = 8; m; m >>= 1) sum += __shfl_xor(sum, m, 16);
    float sv = e / sum;
    if (g < n) {
        sbuf[(long long)g * 16 + k] = sv;
        storeO(sout, fb, (long long)g * 16 + k, sv);
    }
}

// ---- S^T y (16x64), ca = S^T d, colsum = S^T 1 ----
__global__ void k_sty(const float* __restrict__ s, const float* __restrict__ y,
                      const float* __restrict__ dsrc, float* __restrict__ red, int n) {
    int t = threadIdx.x;
    int k4 = t >> 6, f = t & 63;
    float a0 = 0.f, a1 = 0.f, a2 = 0.f, a3 = 0.f;
    for (int node = blockIdx.x; node < n; node += gridDim.x) {
        float yv = y[(long long)node * 64 + f];
        const float* sp = s + (long long)node * 16;
        a0 += sp[k4] * yv;
        a1 += sp[k4 + 4] * yv;
        a2 += sp[k4 + 8] * yv;
        a3 += sp[k4 + 12] * yv;
    }
    atomAddF(&red[RED_STY + k4 * 64 + f], a0);
    atomAddF(&red[RED_STY + (k4 + 4) * 64 + f], a1);
    atomAddF(&red[RED_STY + (k4 + 8) * 64 + f], a2);
    atomAddF(&red[RED_STY + (k4 + 12) * 64 + f], a3);
    if (t < 16) {
        float cs = 0.f, cad = 0.f;
        for (int node = blockIdx.x; node < n; node += gridDim.x) {
            float sv = s[(long long)node * 16 + t];
            cs += sv;
            cad += sv * dsrc[node];
        }
        atomAddF(&red[RED_CA + t], cad);
        atomAddF(&red[RED_CS + t], cs);
    }
}

// ---- ss = S^T S (16x16), thread = (i,j) ----
__global__ void k_ss(const float* __restrict__ s, float* __restrict__ red, int n) {
    int t = threadIdx.x;
    int i = t >> 4, j = t & 15;
    float acc = 0.f;
    for (int node = blockIdx.x; node < n; node += gridDim.x) {
        const float* sp = s + (long long)node * 16;
        acc += sp[i] * sp[j];
    }
    atomAddF(&red[RED_SS + t], acc);
}

// ---- out_adj = sum_e w * outer(s[src], s[dst]); 16-edge tiles ----
__global__ void k_outadj(const void* __restrict__ eidx, const void* __restrict__ ew,
                         const int* __restrict__ flags, const float* __restrict__ s,
                         float* __restrict__ red, int E) {
    __shared__ float S1[256], S2[256], wl[16];
    int t = threadIdx.x;
    int fb = flags[0], fi = flags[1];
    int i = t >> 4, j = t & 15;
    float acc = 0.f;
    int nt = (E + 15) >> 4;
    for (int tile = blockIdx.x; tile < nt; tile += gridDim.x) {
        int e = (tile << 4) + i;
        if (e < E) {
            S1[t] = s[(long long)loadI(eidx, fi, e) * 16 + j];
            S2[t] = s[(long long)loadI(eidx, fi, (long long)E + e) * 16 + j];
            if (j == 0) wl[i] = loadF(ew, fb, e);
        } else {
            S1[t] = 0.f;
            S2[t] = 0.f;
            if (j == 0) wl[i] = 0.f;
        }
        __syncthreads();
#pragma unroll
        for (int el = 0; el < 16; el++) acc += wl[el] * S1[el * 16 + i] * S2[el * 16 + j];
        __syncthreads();
    }
    atomAddF(&red[RED_OADJ + t], acc);
}

__device__ float blockReduceSum256(float v) {
    __shared__ float part[4];
    for (int m = 32; m; m >>= 1) v += __shfl_down(v, m, 64);
    int wid = threadIdx.x >> 6, lane = threadIdx.x & 63;
    if (lane == 0) part[wid] = v;
    __syncthreads();
    v = part[0] + part[1] + part[2] + part[3];
    __syncthreads();
    return v;
}

// ---- single-block finalize: losses + adj postprocess + out features ----
__global__ void k_finalize(const float* __restrict__ red, void* __restrict__ out,
                           const int* __restrict__ flags, int n_nodes, int base) {
    int t = threadIdx.x;
    int fb = flags[0];
    for (int idx = t; idx < 1024; idx += 256)
        storeO(out, fb, base + idx, selu_f(red[RED_STY + idx]));
    int i = t >> 4, j = t & 15;
    float ss_t = red[RED_SS + t];
    float oadj_t = red[RED_OADJ + t];
    float two_m = red[RED_2M];

    float norm_ss = sqrtf(blockReduceSum256(ss_t * ss_t));
    float diff = ss_t / norm_ss - ((i == j) ? 0.25f : 0.f);
    float ortho = sqrtf(blockReduceSum256(diff * diff));
    float trace = blockReduceSum256((i == j) ? oadj_t : 0.f);
    float ca_t = (t < 16) ? red[RED_CA + t] : 0.f;
    float cad = blockReduceSum256(ca_t * ca_t);
    float spectral = -(trace - cad / two_m) / two_m;
    float cs_t = (t < 16) ? red[RED_CS + t] : 0.f;
    float cluster = sqrtf(blockReduceSum256(cs_t * cs_t)) / (float)n_nodes * 4.f - 1.f;

    float a = (i == j) ? 0.f : oadj_t;
    float rs = a;
    for (int m = 8; m; m >>= 1) rs += __shfl_xor(rs, m, 16);
    __shared__ float ddl[16];
    float dd_i = sqrtf(rs) + 1e-15f;
    if (j == 0) ddl[i] = dd_i;
    __syncthreads();
    float aout = a / (dd_i * ddl[j]);
    storeO(out, fb, base + 1024 + t, aout);
    if (t == 0) {
        storeO(out, fb, base + 1280, spectral);
        storeO(out, fb, base + 1281, ortho);
        storeO(out, fb, base + 1282, cluster);
    }
}

extern "C" void kernel_launch(void* const* d_in, const int* in_sizes, int n_in,
                              void* d_out, int out_size, void* d_ws, size_t ws_size,
                              hipStream_t stream) {
    const void* x = d_in[0];
    const void* eidx = d_in[1];
    const void* ew = d_in[2];
    const void* W1 = d_in[3];
    const void* b1 = d_in[4];
    const void* W2 = d_in[5];
    const void* b2 = d_in[6];
    const void* Wp = d_in[7];
    const void* bp = d_in[8];

    const int N = in_sizes[0] / 64;
    const int E = in_sizes[2];

    float* ws = (float*)d_ws;
    float* A = ws;                        // N*64 (linear output h)
    float* B = A + (size_t)N * 64;        // N*64 (agg / activated)
    float* dinv = B + (size_t)N * 64;     // N  (deg then dinv)
    float* dsrc = dinv + N;               // N
    float* coef = dsrc + N;               // E
    float* sbuf = coef + E;               // N*16
    float* red = sbuf + (size_t)N * 16;   // 2048 + flags
    int* flags = (int*)(red + 2048);

    hipMemsetAsync(dinv, 0, sizeof(float) * (size_t)(2 * N), stream);
    hipMemsetAsync(red, 0, sizeof(float) * 2048 + 2 * sizeof(int), stream);

    k_probe<<<1, 256, 0, stream>>>(W1, eidx, flags);
    k_degrees<<<(E + 255) / 256, 256, 0, stream>>>(eidx, ew, flags, dinv, dsrc,
                                                   red + RED_2M, E);
    k_dinv<<<(N + 255) / 256, 256, 0, stream>>>(dinv, N);
    k_coef<<<(E + 255) / 256, 256, 0, stream>>>(eidx, ew, flags, dinv, coef, E);

    // layer 1
    k_gemm64<<<(N + 3) / 4, 256, 0, stream>>>(x, 1, W1, flags, A, N);
    hipMemsetAsync(B, 0, sizeof(float) * (size_t)N * 64, stream);
    int tot = E * 64;
    k_prop<<<(tot + 255) / 256, 256, 0, stream>>>(eidx, flags, coef, A, B, E, tot);
    int tn = N * 64;
    k_finish<<<(tn + 255) / 256, 256, 0, stream>>>(B, A, dinv, b1, flags, tn);

    // layer 2
    k_gemm64<<<(N + 3) / 4, 256, 0, stream>>>(B, 0, W2, flags, A, N);
    hipMemsetAsync(B, 0, sizeof(float) * (size_t)N * 64, stream);
    k_prop<<<(tot + 255) / 256, 256, 0, stream>>>(eidx, flags, coef, A, B, E, tot);
    k_finish<<<(tn + 255) / 256, 256, 0, stream>>>(B, A, dinv, b2, flags, tn);

    // assignment + reductions
    k_softmax<<<(N + 15) / 16, 256, 0, stream>>>(B, Wp, bp, flags, sbuf, d_out, N);
    k_sty<<<512, 256, 0, stream>>>(sbuf, B, dsrc, red, N);
    k_ss<<<512, 256, 0, stream>>>(sbuf, red, N);
    k_outadj<<<1024, 256, 0, stream>>>(eidx, ew, flags, sbuf, red, E);
    k_finalize<<<1, 256, 0, stream>>>(red, d_out, flags, N, N * 16);
}

// Round 3
// 822.385 us; speedup vs baseline: 1.0643x; 1.0643x over previous
//
#include <hip/hip_runtime.h>
#include <hip/hip_bf16.h>

typedef __hip_bfloat16 bf16;
typedef long long i64t;

__device__ __forceinline__ float b2f(bf16 x) { return __bfloat162float(x); }
__device__ __forceinline__ bf16 f2b(float x) { return __float2bfloat16(x); }

// runtime-dtype accessors: isbf/is64 are wave-uniform device flags
__device__ __forceinline__ float loadF(const void* p, int isbf, long long i) {
    return isbf ? b2f(((const bf16*)p)[i]) : ((const float*)p)[i];
}
__device__ __forceinline__ int loadI(const void* p, int is64, long long i) {
    return is64 ? (int)((const i64t*)p)[i] : ((const int*)p)[i];
}
__device__ __forceinline__ void storeO(void* p, int isbf, long long i, float v) {
    if (isbf) ((bf16*)p)[i] = f2b(v);
    else ((float*)p)[i] = v;
}

#define SELU_ALPHA 1.6732632423543772f
#define SELU_SCALE 1.0507009873554805f
__device__ __forceinline__ float selu_f(float x) {
    return SELU_SCALE * (x > 0.f ? x : SELU_ALPHA * (expf(x) - 1.f));
}

__device__ __forceinline__ void atomAddF(float* p, float v) { unsafeAtomicAdd(p, v); }

// red[] layout (floats): [0,1024) sty  [1024,1280) out_adj  [1280,1536) ss
// [1536,1552) ca  [1552,1568) colsum  [1568] two_m ; flags (2 ints) at [2048]
#define RED_STY 0
#define RED_OADJ 1024
#define RED_SS 1280
#define RED_CA 1536
#define RED_CS 1552
#define RED_2M 1568

// ---- dtype probe: flags[0]=floats-are-bf16, flags[1]=indices-are-int64 ----
__global__ void k_probe(const void* W1, const void* eidx, int* flags) {
    __shared__ int sc[2];
    if (threadIdx.x == 0) { sc[0] = 0; sc[1] = 0; }
    __syncthreads();
    const unsigned* w = (const unsigned*)W1;
    int c0 = 0;
    for (int i = threadIdx.x; i < 2048; i += 256) {
        unsigned lo = w[i] & 0xFFFFu;
        unsigned e = (lo >> 7) & 0xFFu;
        if (e == 0u || (e >= 0x60u && e <= 0x8Fu)) c0++;
    }
    const unsigned* iw = (const unsigned*)eidx;
    int c1 = 0;
    for (int i = threadIdx.x; i < 2048; i += 256)
        if (iw[2 * i + 1] == 0u) c1++;
    atomicAdd(&sc[0], c0);
    atomicAdd(&sc[1], c1);
    __syncthreads();
    if (threadIdx.x == 0) {
        flags[0] = sc[0] > 1200 ? 1 : 0;
        flags[1] = sc[1] > 1024 ? 1 : 0;
    }
}

// ---- degrees + dst histogram: deg[dst]+=w, dsrc[src]+=w, cnt[dst]++, two_m+=w ----
__global__ void k_deg_hist(const void* __restrict__ eidx, const void* __restrict__ ew,
                           const int* __restrict__ flags, float* __restrict__ deg,
                           float* __restrict__ dsrc, int* __restrict__ cnt,
                           float* __restrict__ two_m, int E) {
    int g = blockIdx.x * 256 + threadIdx.x;
    int fb = flags[0], fi = flags[1];
    float w = 0.f;
    if (g < E) {
        w = loadF(ew, fb, g);
        int d = loadI(eidx, fi, (long long)E + g);
        atomAddF(&deg[d], w);
        atomicAdd(&cnt[d], 1);
        atomAddF(&dsrc[loadI(eidx, fi, g)], w);
    }
    for (int m = 32; m; m >>= 1) w += __shfl_down(w, m, 64);
    __shared__ float part[4];
    if ((threadIdx.x & 63) == 0) part[threadIdx.x >> 6] = w;
    __syncthreads();
    if (threadIdx.x == 0) atomAddF(two_m, part[0] + part[1] + part[2] + part[3]);
}

// ---- deg -> dinv (in place), deg includes +1 self loop ----
__global__ void k_dinv(float* deg, int n) {
    int i = blockIdx.x * 256 + threadIdx.x;
    if (i < n) deg[i] = rsqrtf(deg[i] + 1.f);
}

// ---- single-block exclusive scan: cnt_ofs[0..n) -> rowptr[0..n], cnt_ofs=prefix ----
__global__ void k_scan(int* __restrict__ cnt_ofs, int* __restrict__ rowptr, int n) {
    __shared__ int part[1024];
    int t = threadIdx.x;
    int chunk = (n + 1023) / 1024;
    int lo = t * chunk, hi = min(lo + chunk, n);
    int s = 0;
    for (int i = lo; i < hi; i++) s += cnt_ofs[i];
    part[t] = s;
    __syncthreads();
    for (int off = 1; off < 1024; off <<= 1) {
        int v = (t >= off) ? part[t - off] : 0;
        __syncthreads();
        part[t] += v;
        __syncthreads();
    }
    int run = t ? part[t - 1] : 0;
    for (int i = lo; i < hi; i++) {
        int c = cnt_ofs[i];
        rowptr[i] = run;
        cnt_ofs[i] = run;
        run += c;
    }
    if (t == 1023) rowptr[n] = part[1023];
}

// ---- scatter edges into CSR order (by dst) with fused coef ----
__global__ void k_scatter(const void* __restrict__ eidx, const void* __restrict__ ew,
                          const int* __restrict__ flags, const float* __restrict__ dinv,
                          int* __restrict__ ofs, int* __restrict__ srcS,
                          float* __restrict__ coefS, int E) {
    int e = blockIdx.x * 256 + threadIdx.x;
    if (e >= E) return;
    int fb = flags[0], fi = flags[1];
    int s = loadI(eidx, fi, e), d = loadI(eidx, fi, (long long)E + e);
    float w = loadF(ew, fb, e);
    int pos = atomicAdd(&ofs[d], 1);
    srcS[pos] = s;
    coefS[pos] = dinv[s] * w * dinv[d];
}

// ---- out[N,64] = in[N,64] @ W[64,64]; in dtype per in_tag (0=f32, 1=flagged) ----
__global__ void k_gemm64(const void* __restrict__ in, int in_tag,
                         const void* __restrict__ W, const int* __restrict__ flags,
                         float* __restrict__ out, int n) {
    __shared__ float Wl[4096];
    __shared__ float Rl[256];
    int t = threadIdx.x;
    int fb = flags[0];
    int inbf = in_tag ? fb : 0;
    for (int idx = t; idx < 4096; idx += 256) Wl[idx] = loadF(W, fb, idx);
    int r0 = blockIdx.x * 4;
    {
        int rl = t >> 6, k = t & 63;
        int r = r0 + rl;
        Rl[t] = (r < n) ? loadF(in, inbf, (long long)r * 64 + k) : 0.f;
    }
    __syncthreads();
    int rl = t >> 6, c = t & 63;
    float acc = 0.f;
#pragma unroll
    for (int k = 0; k < 64; k++) acc += Rl[rl * 64 + k] * Wl[k * 64 + c];
    int r = r0 + rl;
    if (r < n) out[r * 64 + c] = acc;
}

// ---- CSR propagation + self loop + bias + SELU. wave = node, lane = feature ----
__global__ void k_prop_csr(const int* __restrict__ rowptr, const int* __restrict__ srcS,
                           const float* __restrict__ coefS, const float* __restrict__ dinv,
                           const float* __restrict__ hin, const void* __restrict__ b,
                           const int* __restrict__ flags, float* __restrict__ out, int n) {
    int t = threadIdx.x;
    int node = blockIdx.x * 4 + (t >> 6);
    if (node >= n) return;
    int f = t & 63;
    int fb = flags[0];
    int i0 = rowptr[node], i1 = rowptr[node + 1];
    float di = dinv[node];
    float acc = di * di * hin[(long long)node * 64 + f] + loadF(b, fb, f);
    for (int i = i0; i < i1; i++) {
        int s = srcS[i];
        float c = coefS[i];
        acc += c * hin[(long long)s * 64 + f];
    }
    out[(long long)node * 64 + f] = selu_f(acc);
}

// ---- logits + softmax -> sbuf (fp32) + out (flagged dtype) ----
__global__ void k_softmax(const float* __restrict__ y, const void* __restrict__ Wp,
                          const void* __restrict__ bp, const int* __restrict__ flags,
                          float* __restrict__ sbuf, void* __restrict__ sout, int n) {
    __shared__ float Wl[1024];
    __shared__ float bl[16];
    __shared__ float yl[1024];
    int t = threadIdx.x;
    int fb = flags[0];
    for (int idx = t; idx < 1024; idx += 256) Wl[idx] = loadF(Wp, fb, idx);
    if (t < 16) bl[t] = loadF(bp, fb, t);
    int g0 = blockIdx.x * 16;
    for (int idx = t; idx < 1024; idx += 256) {
        int nl = idx >> 6, f = idx & 63;
        int g = g0 + nl;
        yl[idx] = (g < n) ? y[(long long)g * 64 + f] : 0.f;
    }
    __syncthreads();
    int nl = t >> 4, k = t & 15;
    int g = g0 + nl;
    float logit = bl[k];
#pragma unroll
    for (int jj = 0; jj < 64; jj++) logit += yl[nl * 64 + jj] * Wl[jj * 16 + k];
    float mx = logit;
    for (int m = 8; m; m >>= 1) mx = fmaxf(mx, __shfl_xor(mx, m, 16));
    float e = expf(logit - mx);
    float sum = e;
    for (int m = 8; m; m >>= 1) sum += __shfl_xor(sum, m, 16);
    float sv = e / sum;
    if (g < n) {
        sbuf[(long long)g * 16 + k] = sv;
        storeO(sout, fb, (long long)g * 16 + k, sv);
    }
}

// ---- S^T y (16x64) ----
__global__ void k_sty(const float* __restrict__ s, const float* __restrict__ y,
                      float* __restrict__ red, int n) {
    int t = threadIdx.x;
    int k4 = t >> 6, f = t & 63;
    float a0 = 0.f, a1 = 0.f, a2 = 0.f, a3 = 0.f;
    for (int node = blockIdx.x; node < n; node += gridDim.x) {
        float yv = y[(long long)node * 64 + f];
        const float* sp = s + (long long)node * 16;
        a0 += sp[k4] * yv;
        a1 += sp[k4 + 4] * yv;
        a2 += sp[k4 + 8] * yv;
        a3 += sp[k4 + 12] * yv;
    }
    atomAddF(&red[RED_STY + k4 * 64 + f], a0);
    atomAddF(&red[RED_STY + (k4 + 4) * 64 + f], a1);
    atomAddF(&red[RED_STY + (k4 + 8) * 64 + f], a2);
    atomAddF(&red[RED_STY + (k4 + 12) * 64 + f], a3);
}

// ---- ss = S^T S (16x16) + ca = S^T d + colsum ----
__global__ void k_ss(const float* __restrict__ s, const float* __restrict__ dsrc,
                     float* __restrict__ red, int n) {
    int t = threadIdx.x;
    int i = t >> 4, j = t & 15;
    float acc = 0.f, cs = 0.f, ca = 0.f;
    for (int node = blockIdx.x; node < n; node += gridDim.x) {
        const float* sp = s + (long long)node * 16;
        float sj = sp[j];
        acc += sp[i] * sj;
        if (i == 0) {
            cs += sj;
            ca += sj * dsrc[node];
        }
    }
    atomAddF(&red[RED_SS + t], acc);
    if (i == 0) {
        atomAddF(&red[RED_CA + j], ca);
        atomAddF(&red[RED_CS + j], cs);
    }
}

// ---- out_adj via CSR: per-node t = sum_e w*s[src]; out_adj += t (x) s[dst] ----
// block = 16 groups x 16 lanes; group handles nodes with stride gridDim*16
__global__ void k_outadj_csr(const int* __restrict__ rowptr, const int* __restrict__ srcS,
                             const float* __restrict__ coefS, const float* __restrict__ dinv,
                             const float* __restrict__ s, float* __restrict__ red, int n) {
    __shared__ float lacc[256];
    int t = threadIdx.x;
    int g = t >> 4, j = t & 15;
    lacc[t] = 0.f;
    float acc[16];
#pragma unroll
    for (int r = 0; r < 16; r++) acc[r] = 0.f;
    for (int node = blockIdx.x * 16 + g; node < n; node += gridDim.x * 16) {
        int i0 = rowptr[node], i1 = rowptr[node + 1];
        float dinv_d = dinv[node];
        float tv = 0.f;
        for (int i = i0; i < i1; i++) {
            int sidx = srcS[i];
            float w = coefS[i] / (dinv[sidx] * dinv_d);
            tv += w * s[(long long)sidx * 16 + j];
        }
        float sj = s[(long long)node * 16 + j];
#pragma unroll
        for (int r = 0; r < 16; r++) acc[r] += __shfl(tv, r, 16) * sj;
    }
    __syncthreads();
#pragma unroll
    for (int r = 0; r < 16; r++) atomicAdd(&lacc[r * 16 + j], acc[r]);
    __syncthreads();
    if (g < 16) atomAddF(&red[RED_OADJ + t], lacc[t]);
}

__device__ float blockReduceSum256(float v) {
    __shared__ float part[4];
    for (int m = 32; m; m >>= 1) v += __shfl_down(v, m, 64);
    int wid = threadIdx.x >> 6, lane = threadIdx.x & 63;
    if (lane == 0) part[wid] = v;
    __syncthreads();
    v = part[0] + part[1] + part[2] + part[3];
    __syncthreads();
    return v;
}

// ---- single-block finalize: losses + adj postprocess + out features ----
__global__ void k_finalize(const float* __restrict__ red, void* __restrict__ out,
                           const int* __restrict__ flags, int n_nodes, int base) {
    int t = threadIdx.x;
    int fb = flags[0];
    for (int idx = t; idx < 1024; idx += 256)
        storeO(out, fb, base + idx, selu_f(red[RED_STY + idx]));
    int i = t >> 4, j = t & 15;
    float ss_t = red[RED_SS + t];
    float oadj_t = red[RED_OADJ + t];
    float two_m = red[RED_2M];

    float norm_ss = sqrtf(blockReduceSum256(ss_t * ss_t));
    float diff = ss_t / norm_ss - ((i == j) ? 0.25f : 0.f);
    float ortho = sqrtf(blockReduceSum256(diff * diff));
    float trace = blockReduceSum256((i == j) ? oadj_t : 0.f);
    float ca_t = (t < 16) ? red[RED_CA + t] : 0.f;
    float cad = blockReduceSum256(ca_t * ca_t);
    float spectral = -(trace - cad / two_m) / two_m;
    float cs_t = (t < 16) ? red[RED_CS + t] : 0.f;
    float cluster = sqrtf(blockReduceSum256(cs_t * cs_t)) / (float)n_nodes * 4.f - 1.f;

    float a = (i == j) ? 0.f : oadj_t;
    float rs = a;
    for (int m = 8; m; m >>= 1) rs += __shfl_xor(rs, m, 16);
    __shared__ float ddl[16];
    float dd_i = sqrtf(rs) + 1e-15f;
    if (j == 0) ddl[i] = dd_i;
    __syncthreads();
    float aout = a / (dd_i * ddl[j]);
    storeO(out, fb, base + 1024 + t, aout);
    if (t == 0) {
        storeO(out, fb, base + 1280, spectral);
        storeO(out, fb, base + 1281, ortho);
        storeO(out, fb, base + 1282, cluster);
    }
}

extern "C" void kernel_launch(void* const* d_in, const int* in_sizes, int n_in,
                              void* d_out, int out_size, void* d_ws, size_t ws_size,
                              hipStream_t stream) {
    const void* x = d_in[0];
    const void* eidx = d_in[1];
    const void* ew = d_in[2];
    const void* W1 = d_in[3];
    const void* b1 = d_in[4];
    const void* W2 = d_in[5];
    const void* b2 = d_in[6];
    const void* Wp = d_in[7];
    const void* bp = d_in[8];

    const int N = in_sizes[0] / 64;
    const int E = in_sizes[2];

    float* ws = (float*)d_ws;
    float* A = ws;                          // N*64 (linear out; later sbuf alias)
    float* B = A + (size_t)N * 64;          // N*64 (activated layer out)
    float* dinv = B + (size_t)N * 64;       // N   (deg -> dinv)
    float* dsrc = dinv + N;                 // N
    int* rowptr = (int*)(dsrc + N);         // N+1
    int* ofs = rowptr + (N + 1);            // N+1 (hist, then bump pointers)
    int* srcS = ofs + (N + 1);              // E
    float* coefS = (float*)(srcS + E);      // E
    float* red = coefS + E;                 // 2048 + flags
    int* flags = (int*)(red + 2048);
    float* sbuf = A;                        // s[N,16] aliases A (dead by then)

    hipMemsetAsync(dinv, 0, sizeof(float) * (size_t)(2 * N), stream);
    hipMemsetAsync(ofs, 0, sizeof(int) * (size_t)(N + 1), stream);
    hipMemsetAsync(red, 0, sizeof(float) * 2048 + 2 * sizeof(int), stream);

    k_probe<<<1, 256, 0, stream>>>(W1, eidx, flags);
    k_deg_hist<<<(E + 255) / 256, 256, 0, stream>>>(eidx, ew, flags, dinv, dsrc, ofs,
                                                    red + RED_2M, E);
    k_dinv<<<(N + 255) / 256, 256, 0, stream>>>(dinv, N);
    k_scan<<<1, 1024, 0, stream>>>(ofs, rowptr, N);
    k_scatter<<<(E + 255) / 256, 256, 0, stream>>>(eidx, ew, flags, dinv, ofs, srcS,
                                                   coefS, E);

    // layer 1
    k_gemm64<<<(N + 3) / 4, 256, 0, stream>>>(x, 1, W1, flags, A, N);
    k_prop_csr<<<(N + 3) / 4, 256, 0, stream>>>(rowptr, srcS, coefS, dinv, A, b1, flags,
                                                B, N);
    // layer 2
    k_gemm64<<<(N + 3) / 4, 256, 0, stream>>>(B, 0, W2, flags, A, N);
    k_prop_csr<<<(N + 3) / 4, 256, 0, stream>>>(rowptr, srcS, coefS, dinv, A, b2, flags,
                                                B, N);
    // NOTE: prop layer2 writes B while reading A; A=gemm2(B) consumed B first. OK.

    // assignment + reductions (sbuf aliases A — A is dead after layer-2 prop)
    k_softmax<<<(N + 15) / 16, 256, 0, stream>>>(B, Wp, bp, flags, sbuf, d_out, N);
    k_sty<<<512, 256, 0, stream>>>(sbuf, B, red, N);
    k_ss<<<512, 256, 0, stream>>>(sbuf, dsrc, red, N);
    k_outadj_csr<<<256, 256, 0, stream>>>(rowptr, srcS, coefS, dinv, sbuf, red, N);
    k_finalize<<<1, 256, 0, stream>>>(red, d_out, flags, N, N * 16);
}

// Round 4
// 660.685 us; speedup vs baseline: 1.3248x; 1.2447x over previous
//
#include <hip/hip_runtime.h>
#include <hip/hip_bf16.h>

typedef __hip_bfloat16 bf16;
typedef long long i64t;

__device__ __forceinline__ float b2f(bf16 x) { return __bfloat162float(x); }
__device__ __forceinline__ bf16 f2b(float x) { return __float2bfloat16(x); }

// runtime-dtype accessors: isbf/is64 are wave-uniform device flags
__device__ __forceinline__ float loadF(const void* p, int isbf, long long i) {
    return isbf ? b2f(((const bf16*)p)[i]) : ((const float*)p)[i];
}
__device__ __forceinline__ int loadI(const void* p, int is64, long long i) {
    return is64 ? (int)((const i64t*)p)[i] : ((const int*)p)[i];
}
__device__ __forceinline__ void storeO(void* p, int isbf, long long i, float v) {
    if (isbf) ((bf16*)p)[i] = f2b(v);
    else ((float*)p)[i] = v;
}

#define SELU_ALPHA 1.6732632423543772f
#define SELU_SCALE 1.0507009873554805f
__device__ __forceinline__ float selu_f(float x) {
    return SELU_SCALE * (x > 0.f ? x : SELU_ALPHA * (expf(x) - 1.f));
}

__device__ __forceinline__ void atomAddF(float* p, float v) { unsafeAtomicAdd(p, v); }

// red[] layout (floats): [0,1024) sty  [1024,1280) out_adj  [1280,1536) ss
// [1536,1552) ca  [1552,1568) colsum  [1568] two_m ; flags (2 ints) at [2048]
#define RED_STY 0
#define RED_OADJ 1024
#define RED_SS 1280
#define RED_CA 1536
#define RED_CS 1552
#define RED_2M 1568

// ---- dtype probe: flags[0]=floats-are-bf16, flags[1]=indices-are-int64 ----
__global__ void k_probe(const void* W1, const void* eidx, int* flags) {
    __shared__ int sc[2];
    if (threadIdx.x == 0) { sc[0] = 0; sc[1] = 0; }
    __syncthreads();
    const unsigned* w = (const unsigned*)W1;
    int c0 = 0;
    for (int i = threadIdx.x; i < 2048; i += 256) {
        unsigned lo = w[i] & 0xFFFFu;
        unsigned e = (lo >> 7) & 0xFFu;
        if (e == 0u || (e >= 0x60u && e <= 0x8Fu)) c0++;
    }
    const unsigned* iw = (const unsigned*)eidx;
    int c1 = 0;
    for (int i = threadIdx.x; i < 2048; i += 256)
        if (iw[2 * i + 1] == 0u) c1++;
    atomicAdd(&sc[0], c0);
    atomicAdd(&sc[1], c1);
    __syncthreads();
    if (threadIdx.x == 0) {
        flags[0] = sc[0] > 1200 ? 1 : 0;
        flags[1] = sc[1] > 1024 ? 1 : 0;
    }
}

// ---- histogram only: cnt[dst]++ (single atomic per edge) ----
__global__ void k_hist(const void* __restrict__ eidx, const int* __restrict__ flags,
                       int* __restrict__ cnt, int E) {
    int g = blockIdx.x * 256 + threadIdx.x;
    if (g >= E) return;
    int fi = flags[1];
    atomicAdd(&cnt[loadI(eidx, fi, (long long)E + g)], 1);
}

// ---- single-block exclusive scan: cnt_ofs[0..n) -> rowptr[0..n], cnt_ofs=prefix ----
__global__ void k_scan(int* __restrict__ cnt_ofs, int* __restrict__ rowptr, int n) {
    __shared__ int part[1024];
    int t = threadIdx.x;
    int chunk = (n + 1023) / 1024;
    int lo = t * chunk, hi = min(lo + chunk, n);
    int s = 0;
    for (int i = lo; i < hi; i++) s += cnt_ofs[i];
    part[t] = s;
    __syncthreads();
    for (int off = 1; off < 1024; off <<= 1) {
        int v = (t >= off) ? part[t - off] : 0;
        __syncthreads();
        part[t] += v;
        __syncthreads();
    }
    int run = t ? part[t - 1] : 0;
    for (int i = lo; i < hi; i++) {
        int c = cnt_ofs[i];
        rowptr[i] = run;
        cnt_ofs[i] = run;
        run += c;
    }
    if (t == 1023) rowptr[n] = part[1023];
}

// ---- scatter edges into CSR order (by dst), packed {src, w} ----
__global__ void k_scatter(const void* __restrict__ eidx, const void* __restrict__ ew,
                          const int* __restrict__ flags, int* __restrict__ ofs,
                          uint2* __restrict__ srcW, int E) {
    int e = blockIdx.x * 256 + threadIdx.x;
    if (e >= E) return;
    int fb = flags[0], fi = flags[1];
    int s = loadI(eidx, fi, e), d = loadI(eidx, fi, (long long)E + e);
    float w = loadF(ew, fb, e);
    int pos = atomicAdd(&ofs[d], 1);
    srcW[pos] = make_uint2((unsigned)s, __float_as_uint(w));
}

// ---- deg from CSR rows -> dinv; two_m block-reduced. 16 lanes per node ----
__global__ void k_deg(const int* __restrict__ rowptr, const uint2* __restrict__ srcW,
                      float* __restrict__ dinv, float* __restrict__ two_m, int n) {
    int t = threadIdx.x;
    int g = t >> 4, j = t & 15;
    int node = blockIdx.x * 16 + g;
    float wsum = 0.f;
    if (node < n) {
        int i0 = rowptr[node], i1 = rowptr[node + 1];
        for (int i = i0 + j; i < i1; i += 16) wsum += __uint_as_float(srcW[i].y);
        float r = wsum;
        for (int m = 8; m; m >>= 1) r += __shfl_xor(r, m, 16);
        if (j == 0) dinv[node] = rsqrtf(r + 1.f);
    }
    // block reduce wsum for two_m (all threads participate)
    __shared__ float part[4];
    float v = wsum;
    for (int m = 32; m; m >>= 1) v += __shfl_down(v, m, 64);
    int wid = t >> 6, lane = t & 63;
    if (lane == 0) part[wid] = v;
    __syncthreads();
    if (t == 0) atomAddF(two_m, part[0] + part[1] + part[2] + part[3]);
}

// ---- out[N,64] = in[N,64] @ W[64,64]; 32 rows/block, 8 outputs/thread ----
__global__ void k_gemm64(const void* __restrict__ in, int in_tag,
                         const void* __restrict__ W, const int* __restrict__ flags,
                         float* __restrict__ out, int n) {
    __shared__ float Wl[4096];
    __shared__ float Rl[2048];
    int t = threadIdx.x;
    int fb = flags[0];
    int inbf = in_tag ? fb : 0;
    for (int idx = t; idx < 4096; idx += 256) Wl[idx] = loadF(W, fb, idx);
    int r0 = blockIdx.x * 32;
    for (int idx = t; idx < 2048; idx += 256) {
        int rl = idx >> 6, k = idx & 63;
        int r = r0 + rl;
        Rl[idx] = (r < n) ? loadF(in, inbf, (long long)r * 64 + k) : 0.f;
    }
    __syncthreads();
    int rl = t >> 6, c = t & 63;
    float acc[8];
#pragma unroll
    for (int u = 0; u < 8; u++) acc[u] = 0.f;
    for (int k = 0; k < 64; k++) {
        float wv = Wl[k * 64 + c];
#pragma unroll
        for (int u = 0; u < 8; u++) acc[u] += Rl[(rl + (u << 2)) * 64 + k] * wv;
    }
#pragma unroll
    for (int u = 0; u < 8; u++) {
        int r = r0 + rl + (u << 2);
        if (r < n) out[(long long)r * 64 + c] = acc[u];
    }
}

// ---- CSR propagation + self loop + bias + SELU. wave = node, lane = feature ----
__global__ void k_prop_csr(const int* __restrict__ rowptr, const uint2* __restrict__ srcW,
                           const float* __restrict__ dinv, const float* __restrict__ hin,
                           const void* __restrict__ b, const int* __restrict__ flags,
                           float* __restrict__ out, int n) {
    int t = threadIdx.x;
    int node = blockIdx.x * 4 + (t >> 6);
    if (node >= n) return;
    int f = t & 63;
    int fb = flags[0];
    int i0 = rowptr[node], i1 = rowptr[node + 1];
    float di = dinv[node];
    float accE = 0.f;
    for (int base = i0; base < i1; base += 64) {
        int idx = base + f;
        uint2 p = (idx < i1) ? srcW[idx] : make_uint2(0u, 0u);
        float cw = __uint_as_float(p.y) * dinv[p.x];  // w * dinv[src]
        int m = min(i1 - base, 64);
        for (int j = 0; j < m; j++) {
            int s = __shfl((int)p.x, j, 64);
            float c = __shfl(cw, j, 64);
            accE += c * hin[(long long)s * 64 + f];
        }
    }
    float v = di * accE + di * di * hin[(long long)node * 64 + f] + loadF(b, fb, f);
    out[(long long)node * 64 + f] = selu_f(v);
}

// ---- logits + softmax -> sbuf (fp32) + out (flagged dtype) ----
__global__ void k_softmax(const float* __restrict__ y, const void* __restrict__ Wp,
                          const void* __restrict__ bp, const int* __restrict__ flags,
                          float* __restrict__ sbuf, void* __restrict__ sout, int n) {
    __shared__ float Wl[1024];
    __shared__ float bl[16];
    __shared__ float yl[1024];
    int t = threadIdx.x;
    int fb = flags[0];
    for (int idx = t; idx < 1024; idx += 256) Wl[idx] = loadF(Wp, fb, idx);
    if (t < 16) bl[t] = loadF(bp, fb, t);
    int g0 = blockIdx.x * 16;
    for (int idx = t; idx < 1024; idx += 256) {
        int nl = idx >> 6, f = idx & 63;
        int g = g0 + nl;
        yl[idx] = (g < n) ? y[(long long)g * 64 + f] : 0.f;
    }
    __syncthreads();
    int nl = t >> 4, k = t & 15;
    int g = g0 + nl;
    float logit = bl[k];
#pragma unroll
    for (int jj = 0; jj < 64; jj++) logit += yl[nl * 64 + jj] * Wl[jj * 16 + k];
    float mx = logit;
    for (int m = 8; m; m >>= 1) mx = fmaxf(mx, __shfl_xor(mx, m, 16));
    float e = expf(logit - mx);
    float sum = e;
    for (int m = 8; m; m >>= 1) sum += __shfl_xor(sum, m, 16);
    float sv = e / sum;
    if (g < n) {
        sbuf[(long long)g * 16 + k] = sv;
        storeO(sout, fb, (long long)g * 16 + k, sv);
    }
}

// ---- S^T y (16x64) ----
__global__ void k_sty(const float* __restrict__ s, const float* __restrict__ y,
                      float* __restrict__ red, int n) {
    int t = threadIdx.x;
    int k4 = t >> 6, f = t & 63;
    float a0 = 0.f, a1 = 0.f, a2 = 0.f, a3 = 0.f;
    for (int node = blockIdx.x; node < n; node += gridDim.x) {
        float yv = y[(long long)node * 64 + f];
        const float* sp = s + (long long)node * 16;
        a0 += sp[k4] * yv;
        a1 += sp[k4 + 4] * yv;
        a2 += sp[k4 + 8] * yv;
        a3 += sp[k4 + 12] * yv;
    }
    atomAddF(&red[RED_STY + k4 * 64 + f], a0);
    atomAddF(&red[RED_STY + (k4 + 4) * 64 + f], a1);
    atomAddF(&red[RED_STY + (k4 + 8) * 64 + f], a2);
    atomAddF(&red[RED_STY + (k4 + 12) * 64 + f], a3);
}

// ---- ss = S^T S (16x16) ----
__global__ void k_ss(const float* __restrict__ s, float* __restrict__ red, int n) {
    int t = threadIdx.x;
    int i = t >> 4, j = t & 15;
    float acc = 0.f;
    for (int node = blockIdx.x; node < n; node += gridDim.x) {
        const float* sp = s + (long long)node * 16;
        acc += sp[i] * sp[j];
    }
    atomAddF(&red[RED_SS + t], acc);
}

// ---- out_adj via CSR + ca + colsum. 16-lane groups, packed srcW ----
__global__ void k_outadj_csr(const int* __restrict__ rowptr, const uint2* __restrict__ srcW,
                             const float* __restrict__ s, float* __restrict__ red, int n) {
    __shared__ float lacc[256];
    __shared__ float sca[16];
    __shared__ float scs[16];
    int t = threadIdx.x;
    int g = t >> 4, j = t & 15;
    lacc[t] = 0.f;
    if (t < 16) { sca[t] = 0.f; scs[t] = 0.f; }
    __syncthreads();
    float acc[16];
#pragma unroll
    for (int r = 0; r < 16; r++) acc[r] = 0.f;
    float catot = 0.f, cstot = 0.f;
    for (int node = blockIdx.x * 16 + g; node < n; node += gridDim.x * 16) {
        int i0 = rowptr[node], i1 = rowptr[node + 1];
        float tv = 0.f;
        for (int base = i0; base < i1; base += 16) {
            int idx = base + j;
            uint2 p = (idx < i1) ? srcW[idx] : make_uint2(0u, 0u);
            float wl = __uint_as_float(p.y);
            int m = min(i1 - base, 16);
            for (int r = 0; r < m; r++) {
                int sidx = __shfl((int)p.x, r, 16);
                float w = __shfl(wl, r, 16);
                tv += w * s[(long long)sidx * 16 + j];
            }
        }
        float sj = s[(long long)node * 16 + j];
        catot += tv;
        cstot += sj;
#pragma unroll
        for (int r = 0; r < 16; r++) acc[r] += __shfl(tv, r, 16) * sj;
    }
#pragma unroll
    for (int r = 0; r < 16; r++) atomicAdd(&lacc[r * 16 + j], acc[r]);
    atomicAdd(&sca[j], catot);
    atomicAdd(&scs[j], cstot);
    __syncthreads();
    atomAddF(&red[RED_OADJ + t], lacc[t]);
    if (t < 16) {
        atomAddF(&red[RED_CA + t], sca[t]);
        atomAddF(&red[RED_CS + t], scs[t]);
    }
}

__device__ float blockReduceSum256(float v) {
    __shared__ float part[4];
    for (int m = 32; m; m >>= 1) v += __shfl_down(v, m, 64);
    int wid = threadIdx.x >> 6, lane = threadIdx.x & 63;
    if (lane == 0) part[wid] = v;
    __syncthreads();
    v = part[0] + part[1] + part[2] + part[3];
    __syncthreads();
    return v;
}

// ---- single-block finalize: losses + adj postprocess + out features ----
__global__ void k_finalize(const float* __restrict__ red, void* __restrict__ out,
                           const int* __restrict__ flags, int n_nodes, int base) {
    int t = threadIdx.x;
    int fb = flags[0];
    for (int idx = t; idx < 1024; idx += 256)
        storeO(out, fb, base + idx, selu_f(red[RED_STY + idx]));
    int i = t >> 4, j = t & 15;
    float ss_t = red[RED_SS + t];
    float oadj_t = red[RED_OADJ + t];
    float two_m = red[RED_2M];

    float norm_ss = sqrtf(blockReduceSum256(ss_t * ss_t));
    float diff = ss_t / norm_ss - ((i == j) ? 0.25f : 0.f);
    float ortho = sqrtf(blockReduceSum256(diff * diff));
    float trace = blockReduceSum256((i == j) ? oadj_t : 0.f);
    float ca_t = (t < 16) ? red[RED_CA + t] : 0.f;
    float cad = blockReduceSum256(ca_t * ca_t);
    float spectral = -(trace - cad / two_m) / two_m;
    float cs_t = (t < 16) ? red[RED_CS + t] : 0.f;
    float cluster = sqrtf(blockReduceSum256(cs_t * cs_t)) / (float)n_nodes * 4.f - 1.f;

    float a = (i == j) ? 0.f : oadj_t;
    float rs = a;
    for (int m = 8; m; m >>= 1) rs += __shfl_xor(rs, m, 16);
    __shared__ float ddl[16];
    float dd_i = sqrtf(rs) + 1e-15f;
    if (j == 0) ddl[i] = dd_i;
    __syncthreads();
    float aout = a / (dd_i * ddl[j]);
    storeO(out, fb, base + 1024 + t, aout);
    if (t == 0) {
        storeO(out, fb, base + 1280, spectral);
        storeO(out, fb, base + 1281, ortho);
        storeO(out, fb, base + 1282, cluster);
    }
}

extern "C" void kernel_launch(void* const* d_in, const int* in_sizes, int n_in,
                              void* d_out, int out_size, void* d_ws, size_t ws_size,
                              hipStream_t stream) {
    const void* x = d_in[0];
    const void* eidx = d_in[1];
    const void* ew = d_in[2];
    const void* W1 = d_in[3];
    const void* b1 = d_in[4];
    const void* W2 = d_in[5];
    const void* b2 = d_in[6];
    const void* Wp = d_in[7];
    const void* bp = d_in[8];

    const int N = in_sizes[0] / 64;
    const int E = in_sizes[2];

    float* ws = (float*)d_ws;
    float* A = ws;                          // N*64 (linear out; later sbuf alias)
    float* B = A + (size_t)N * 64;          // N*64 (activated layer out)
    float* dinv = B + (size_t)N * 64;       // N
    int* rowptr = (int*)(dinv + N);         // N+1
    int* ofs = rowptr + (N + 1);            // N+1 (hist, then bump pointers)
    float* red = (float*)(ofs + (N + 1));   // 2048 + flags
    int* flags = (int*)(red + 2048);        // 2
    size_t off_ints = (size_t)((int*)(flags + 2) - (int*)ws);
    off_ints = (off_ints + 1) & ~(size_t)1;  // 8B align
    uint2* srcW = (uint2*)((int*)ws + off_ints);  // E packed {src, w}
    float* sbuf = A;                        // s[N,16] aliases A (dead by then)

    hipMemsetAsync(ofs, 0, sizeof(int) * (size_t)(N + 1), stream);
    hipMemsetAsync(red, 0, sizeof(float) * 2048 + 2 * sizeof(int), stream);

    k_probe<<<1, 256, 0, stream>>>(W1, eidx, flags);
    k_hist<<<(E + 255) / 256, 256, 0, stream>>>(eidx, flags, ofs, E);
    k_scan<<<1, 1024, 0, stream>>>(ofs, rowptr, N);
    k_scatter<<<(E + 255) / 256, 256, 0, stream>>>(eidx, ew, flags, ofs, srcW, E);
    k_deg<<<(N + 15) / 16, 256, 0, stream>>>(rowptr, srcW, dinv, red + RED_2M, N);

    // layer 1
    k_gemm64<<<(N + 31) / 32, 256, 0, stream>>>(x, 1, W1, flags, A, N);
    k_prop_csr<<<(N + 3) / 4, 256, 0, stream>>>(rowptr, srcW, dinv, A, b1, flags, B, N);
    // layer 2
    k_gemm64<<<(N + 31) / 32, 256, 0, stream>>>(B, 0, W2, flags, A, N);
    k_prop_csr<<<(N + 3) / 4, 256, 0, stream>>>(rowptr, srcW, dinv, A, b2, flags, B, N);

    // assignment + reductions (sbuf aliases A — A is dead after layer-2 prop)
    k_softmax<<<(N + 15) / 16, 256, 0, stream>>>(B, Wp, bp, flags, sbuf, d_out, N);
    k_sty<<<512, 256, 0, stream>>>(sbuf, B, red, N);
    k_ss<<<512, 256, 0, stream>>>(sbuf, red, N);
    k_outadj_csr<<<256, 256, 0, stream>>>(rowptr, srcW, sbuf, red, N);
    k_finalize<<<1, 256, 0, stream>>>(red, d_out, flags, N, N * 16);
}

// Round 5
// 559.887 us; speedup vs baseline: 1.5633x; 1.1800x over previous
//
#include <hip/hip_runtime.h>
#include <hip/hip_bf16.h>

typedef __hip_bfloat16 bf16;
typedef long long i64t;

__device__ __forceinline__ float b2f(bf16 x) { return __bfloat162float(x); }
__device__ __forceinline__ bf16 f2b(float x) { return __float2bfloat16(x); }

// runtime-dtype accessors: isbf/is64 are wave-uniform device flags
__device__ __forceinline__ float loadF(const void* p, int isbf, long long i) {
    return isbf ? b2f(((const bf16*)p)[i]) : ((const float*)p)[i];
}
__device__ __forceinline__ int loadI(const void* p, int is64, long long i) {
    return is64 ? (int)((const i64t*)p)[i] : ((const int*)p)[i];
}
__device__ __forceinline__ void storeO(void* p, int isbf, long long i, float v) {
    if (isbf) ((bf16*)p)[i] = f2b(v);
    else ((float*)p)[i] = v;
}

#define SELU_ALPHA 1.6732632423543772f
#define SELU_SCALE 1.0507009873554805f
__device__ __forceinline__ float selu_f(float x) {
    return SELU_SCALE * (x > 0.f ? x : SELU_ALPHA * (expf(x) - 1.f));
}

__device__ __forceinline__ void atomAddF(float* p, float v) { unsafeAtomicAdd(p, v); }

// red[] layout (floats): [0,1024) sty  [1024,1280) out_adj  [1280,1536) ss
// [1536,1552) ca  [1552,1568) colsum  [1568] two_m ; flags (2 ints) at [2048]
#define RED_STY 0
#define RED_OADJ 1024
#define RED_SS 1280
#define RED_CA 1536
#define RED_CS 1552
#define RED_2M 1568

// ---- dtype probe: flags[0]=floats-are-bf16, flags[1]=indices-are-int64 ----
__global__ void k_probe(const void* W1, const void* eidx, int* flags) {
    __shared__ int sc[2];
    if (threadIdx.x == 0) { sc[0] = 0; sc[1] = 0; }
    __syncthreads();
    const unsigned* w = (const unsigned*)W1;
    int c0 = 0;
    for (int i = threadIdx.x; i < 2048; i += 256) {
        unsigned lo = w[i] & 0xFFFFu;
        unsigned e = (lo >> 7) & 0xFFu;
        if (e == 0u || (e >= 0x60u && e <= 0x8Fu)) c0++;
    }
    const unsigned* iw = (const unsigned*)eidx;
    int c1 = 0;
    for (int i = threadIdx.x; i < 2048; i += 256)
        if (iw[2 * i + 1] == 0u) c1++;
    atomicAdd(&sc[0], c0);
    atomicAdd(&sc[1], c1);
    __syncthreads();
    if (threadIdx.x == 0) {
        flags[0] = sc[0] > 1200 ? 1 : 0;
        flags[1] = sc[1] > 1024 ? 1 : 0;
    }
}

// ---- histogram only: cnt[dst]++ (single atomic per edge) ----
__global__ void k_hist(const void* __restrict__ eidx, const int* __restrict__ flags,
                       int* __restrict__ cnt, int E) {
    int g = blockIdx.x * 256 + threadIdx.x;
    if (g >= E) return;
    int fi = flags[1];
    atomicAdd(&cnt[loadI(eidx, fi, (long long)E + g)], 1);
}

// ---- 3-phase multi-block exclusive scan (tile = 1024 = 256 thr x 4) ----
__global__ void k_scan1(const int* __restrict__ cnt, int* __restrict__ rowptr,
                        int* __restrict__ bsum, int n) {
    __shared__ int part[256];
    int t = threadIdx.x;
    int base = blockIdx.x * 1024 + t * 4;
    int v[4];
    int s = 0;
#pragma unroll
    for (int u = 0; u < 4; u++) {
        int i = base + u;
        v[u] = (i < n) ? cnt[i] : 0;
        s += v[u];
    }
    part[t] = s;
    __syncthreads();
    for (int off = 1; off < 256; off <<= 1) {
        int x = (t >= off) ? part[t - off] : 0;
        __syncthreads();
        part[t] += x;
        __syncthreads();
    }
    int run = t ? part[t - 1] : 0;
#pragma unroll
    for (int u = 0; u < 4; u++) {
        int i = base + u;
        if (i < n) rowptr[i] = run;
        run += v[u];
    }
    if (t == 255) bsum[blockIdx.x] = part[255];
}

__global__ void k_scan2(const int* __restrict__ bsum, int* __restrict__ bpre,
                        int* __restrict__ rowptr, int nb, int n) {
    __shared__ int part[256];
    int t = threadIdx.x;
    part[t] = (t < nb) ? bsum[t] : 0;
    __syncthreads();
    for (int off = 1; off < 256; off <<= 1) {
        int x = (t >= off) ? part[t - off] : 0;
        __syncthreads();
        part[t] += x;
        __syncthreads();
    }
    if (t < nb) bpre[t] = t ? part[t - 1] : 0;
    if (t == 255) rowptr[n] = part[255];
}

__global__ void k_scan3(int* __restrict__ rowptr, int* __restrict__ ofs,
                        const int* __restrict__ bpre, int n) {
    int t = threadIdx.x;
    int add = bpre[blockIdx.x];
    int base = blockIdx.x * 1024 + t * 4;
#pragma unroll
    for (int u = 0; u < 4; u++) {
        int i = base + u;
        if (i < n) {
            int r = rowptr[i] + add;
            rowptr[i] = r;
            ofs[i] = r;
        }
    }
}

// ---- scatter edges into CSR order (by dst), packed {src, w} ----
__global__ void k_scatter(const void* __restrict__ eidx, const void* __restrict__ ew,
                          const int* __restrict__ flags, int* __restrict__ ofs,
                          uint2* __restrict__ srcW, int E) {
    int e = blockIdx.x * 256 + threadIdx.x;
    if (e >= E) return;
    int fb = flags[0], fi = flags[1];
    int s = loadI(eidx, fi, e), d = loadI(eidx, fi, (long long)E + e);
    float w = loadF(ew, fb, e);
    int pos = atomicAdd(&ofs[d], 1);
    srcW[pos] = make_uint2((unsigned)s, __float_as_uint(w));
}

// ---- deg from CSR rows -> dinv; two_m block-reduced. 16 lanes per node ----
__global__ void k_deg(const int* __restrict__ rowptr, const uint2* __restrict__ srcW,
                      float* __restrict__ dinv, float* __restrict__ two_m, int n) {
    int t = threadIdx.x;
    int g = t >> 4, j = t & 15;
    int node = blockIdx.x * 16 + g;
    float wsum = 0.f;
    if (node < n) {
        int i0 = rowptr[node], i1 = rowptr[node + 1];
        for (int i = i0 + j; i < i1; i += 16) wsum += __uint_as_float(srcW[i].y);
        float r = wsum;
        for (int m = 8; m; m >>= 1) r += __shfl_xor(r, m, 16);
        if (j == 0) dinv[node] = rsqrtf(r + 1.f);
    }
    __shared__ float part[4];
    float v = wsum;
    for (int m = 32; m; m >>= 1) v += __shfl_down(v, m, 64);
    int wid = t >> 6, lane = t & 63;
    if (lane == 0) part[wid] = v;
    __syncthreads();
    if (t == 0) atomAddF(two_m, part[0] + part[1] + part[2] + part[3]);
}

// ---- out[N,64] = in[N,64] @ W[64,64]; 32 rows/block, 8 outputs/thread ----
__global__ void k_gemm64(const void* __restrict__ in, int in_tag,
                         const void* __restrict__ W, const int* __restrict__ flags,
                         float* __restrict__ out, int n) {
    __shared__ float Wl[4096];
    __shared__ float Rl[2048];
    int t = threadIdx.x;
    int fb = flags[0];
    int inbf = in_tag ? fb : 0;
    for (int idx = t; idx < 4096; idx += 256) Wl[idx] = loadF(W, fb, idx);
    int r0 = blockIdx.x * 32;
    for (int idx = t; idx < 2048; idx += 256) {
        int rl = idx >> 6, k = idx & 63;
        int r = r0 + rl;
        Rl[idx] = (r < n) ? loadF(in, inbf, (long long)r * 64 + k) : 0.f;
    }
    __syncthreads();
    int rl = t >> 6, c = t & 63;
    float acc[8];
#pragma unroll
    for (int u = 0; u < 8; u++) acc[u] = 0.f;
    for (int k = 0; k < 64; k++) {
        float wv = Wl[k * 64 + c];
#pragma unroll
        for (int u = 0; u < 8; u++) acc[u] += Rl[(rl + (u << 2)) * 64 + k] * wv;
    }
#pragma unroll
    for (int u = 0; u < 8; u++) {
        int r = r0 + rl + (u << 2);
        if (r < n) out[(long long)r * 64 + c] = acc[u];
    }
}

// ---- CSR propagation + self loop + bias + SELU. wave = node, lane = feature ----
__global__ void k_prop_csr(const int* __restrict__ rowptr, const uint2* __restrict__ srcW,
                           const float* __restrict__ dinv, const float* __restrict__ hin,
                           const void* __restrict__ b, const int* __restrict__ flags,
                           float* __restrict__ out, int n) {
    int t = threadIdx.x;
    int node = blockIdx.x * 4 + (t >> 6);
    if (node >= n) return;
    int f = t & 63;
    int fb = flags[0];
    int i0 = rowptr[node], i1 = rowptr[node + 1];
    float di = dinv[node];
    float accE = 0.f;
    for (int base = i0; base < i1; base += 64) {
        int idx = base + f;
        uint2 p = (idx < i1) ? srcW[idx] : make_uint2(0u, 0u);
        float cw = __uint_as_float(p.y) * dinv[p.x];  // w * dinv[src]
        int m = min(i1 - base, 64);
        for (int j = 0; j < m; j++) {
            int s = __shfl((int)p.x, j, 64);
            float c = __shfl(cw, j, 64);
            accE += c * hin[(long long)s * 64 + f];
        }
    }
    float v = di * accE + di * di * hin[(long long)node * 64 + f] + loadF(b, fb, f);
    out[(long long)node * 64 + f] = selu_f(v);
}

// ---- logits + softmax -> sbuf (fp32) + out (flagged dtype) ----
__global__ void k_softmax(const float* __restrict__ y, const void* __restrict__ Wp,
                          const void* __restrict__ bp, const int* __restrict__ flags,
                          float* __restrict__ sbuf, void* __restrict__ sout, int n) {
    __shared__ float Wl[1024];
    __shared__ float bl[16];
    __shared__ float yl[1024];
    int t = threadIdx.x;
    int fb = flags[0];
    for (int idx = t; idx < 1024; idx += 256) Wl[idx] = loadF(Wp, fb, idx);
    if (t < 16) bl[t] = loadF(bp, fb, t);
    int g0 = blockIdx.x * 16;
    for (int idx = t; idx < 1024; idx += 256) {
        int nl = idx >> 6, f = idx & 63;
        int g = g0 + nl;
        yl[idx] = (g < n) ? y[(long long)g * 64 + f] : 0.f;
    }
    __syncthreads();
    int nl = t >> 4, k = t & 15;
    int g = g0 + nl;
    float logit = bl[k];
#pragma unroll
    for (int jj = 0; jj < 64; jj++) logit += yl[nl * 64 + jj] * Wl[jj * 16 + k];
    float mx = logit;
    for (int m = 8; m; m >>= 1) mx = fmaxf(mx, __shfl_xor(mx, m, 16));
    float e = expf(logit - mx);
    float sum = e;
    for (int m = 8; m; m >>= 1) sum += __shfl_xor(sum, m, 16);
    float sv = e / sum;
    if (g < n) {
        sbuf[(long long)g * 16 + k] = sv;
        storeO(sout, fb, (long long)g * 16 + k, sv);
    }
}

// ---- S^T y (16x64) ----
__global__ void k_sty(const float* __restrict__ s, const float* __restrict__ y,
                      float* __restrict__ red, int n) {
    int t = threadIdx.x;
    int k4 = t >> 6, f = t & 63;
    float a0 = 0.f, a1 = 0.f, a2 = 0.f, a3 = 0.f;
    for (int node = blockIdx.x; node < n; node += gridDim.x) {
        float yv = y[(long long)node * 64 + f];
        const float* sp = s + (long long)node * 16;
        a0 += sp[k4] * yv;
        a1 += sp[k4 + 4] * yv;
        a2 += sp[k4 + 8] * yv;
        a3 += sp[k4 + 12] * yv;
    }
    atomAddF(&red[RED_STY + k4 * 64 + f], a0);
    atomAddF(&red[RED_STY + (k4 + 4) * 64 + f], a1);
    atomAddF(&red[RED_STY + (k4 + 8) * 64 + f], a2);
    atomAddF(&red[RED_STY + (k4 + 12) * 64 + f], a3);
}

// ---- ss = S^T S (16x16) ----
__global__ void k_ss(const float* __restrict__ s, float* __restrict__ red, int n) {
    int t = threadIdx.x;
    int i = t >> 4, j = t & 15;
    float acc = 0.f;
    for (int node = blockIdx.x; node < n; node += gridDim.x) {
        const float* sp = s + (long long)node * 16;
        acc += sp[i] * sp[j];
    }
    atomAddF(&red[RED_SS + t], acc);
}

// ---- out_adj via CSR + ca + colsum. 16-lane groups, packed srcW ----
__global__ void k_outadj_csr(const int* __restrict__ rowptr, const uint2* __restrict__ srcW,
                             const float* __restrict__ s, float* __restrict__ red, int n) {
    __shared__ float lacc[256];
    __shared__ float sca[16];
    __shared__ float scs[16];
    int t = threadIdx.x;
    int g = t >> 4, j = t & 15;
    lacc[t] = 0.f;
    if (t < 16) { sca[t] = 0.f; scs[t] = 0.f; }
    __syncthreads();
    float acc[16];
#pragma unroll
    for (int r = 0; r < 16; r++) acc[r] = 0.f;
    float catot = 0.f, cstot = 0.f;
    for (int node = blockIdx.x * 16 + g; node < n; node += gridDim.x * 16) {
        int i0 = rowptr[node], i1 = rowptr[node + 1];
        float tv = 0.f;
        for (int base = i0; base < i1; base += 16) {
            int idx = base + j;
            uint2 p = (idx < i1) ? srcW[idx] : make_uint2(0u, 0u);
            float wl = __uint_as_float(p.y);
            int m = min(i1 - base, 16);
            for (int r = 0; r < m; r++) {
                int sidx = __shfl((int)p.x, r, 16);
                float w = __shfl(wl, r, 16);
                tv += w * s[(long long)sidx * 16 + j];
            }
        }
        float sj = s[(long long)node * 16 + j];
        catot += tv;
        cstot += sj;
#pragma unroll
        for (int r = 0; r < 16; r++) acc[r] += __shfl(tv, r, 16) * sj;
    }
#pragma unroll
    for (int r = 0; r < 16; r++) atomicAdd(&lacc[r * 16 + j], acc[r]);
    atomicAdd(&sca[j], catot);
    atomicAdd(&scs[j], cstot);
    __syncthreads();
    atomAddF(&red[RED_OADJ + t], lacc[t]);
    if (t < 16) {
        atomAddF(&red[RED_CA + t], sca[t]);
        atomAddF(&red[RED_CS + t], scs[t]);
    }
}

__device__ float blockReduceSum256(float v) {
    __shared__ float part[4];
    for (int m = 32; m; m >>= 1) v += __shfl_down(v, m, 64);
    int wid = threadIdx.x >> 6, lane = threadIdx.x & 63;
    if (lane == 0) part[wid] = v;
    __syncthreads();
    v = part[0] + part[1] + part[2] + part[3];
    __syncthreads();
    return v;
}

// ---- single-block finalize: losses + adj postprocess + out features ----
__global__ void k_finalize(const float* __restrict__ red, void* __restrict__ out,
                           const int* __restrict__ flags, int n_nodes, int base) {
    int t = threadIdx.x;
    int fb = flags[0];
    for (int idx = t; idx < 1024; idx += 256)
        storeO(out, fb, base + idx, selu_f(red[RED_STY + idx]));
    int i = t >> 4, j = t & 15;
    float ss_t = red[RED_SS + t];
    float oadj_t = red[RED_OADJ + t];
    float two_m = red[RED_2M];

    float norm_ss = sqrtf(blockReduceSum256(ss_t * ss_t));
    float diff = ss_t / norm_ss - ((i == j) ? 0.25f : 0.f);
    float ortho = sqrtf(blockReduceSum256(diff * diff));
    float trace = blockReduceSum256((i == j) ? oadj_t : 0.f);
    float ca_t = (t < 16) ? red[RED_CA + t] : 0.f;
    float cad = blockReduceSum256(ca_t * ca_t);
    float spectral = -(trace - cad / two_m) / two_m;
    float cs_t = (t < 16) ? red[RED_CS + t] : 0.f;
    float cluster = sqrtf(blockReduceSum256(cs_t * cs_t)) / (float)n_nodes * 4.f - 1.f;

    float a = (i == j) ? 0.f : oadj_t;
    float rs = a;
    for (int m = 8; m; m >>= 1) rs += __shfl_xor(rs, m, 16);
    __shared__ float ddl[16];
    float dd_i = sqrtf(rs) + 1e-15f;
    if (j == 0) ddl[i] = dd_i;
    __syncthreads();
    float aout = a / (dd_i * ddl[j]);
    storeO(out, fb, base + 1024 + t, aout);
    if (t == 0) {
        storeO(out, fb, base + 1280, spectral);
        storeO(out, fb, base + 1281, ortho);
        storeO(out, fb, base + 1282, cluster);
    }
}

extern "C" void kernel_launch(void* const* d_in, const int* in_sizes, int n_in,
                              void* d_out, int out_size, void* d_ws, size_t ws_size,
                              hipStream_t stream) {
    const void* x = d_in[0];
    const void* eidx = d_in[1];
    const void* ew = d_in[2];
    const void* W1 = d_in[3];
    const void* b1 = d_in[4];
    const void* W2 = d_in[5];
    const void* b2 = d_in[6];
    const void* Wp = d_in[7];
    const void* bp = d_in[8];

    const int N = in_sizes[0] / 64;
    const int E = in_sizes[2];

    float* ws = (float*)d_ws;
    float* A = ws;                          // N*64 (linear out; later sbuf alias)
    float* B = A + (size_t)N * 64;          // N*64 (activated layer out)
    float* dinv = B + (size_t)N * 64;       // N
    int* rowptr = (int*)(dinv + N);         // N+1
    int* ofs = rowptr + (N + 1);            // N+1 (hist counts, then bump ptrs)
    float* red = (float*)(ofs + (N + 1));   // 2048 + flags
    int* flags = (int*)(red + 2048);        // 2
    int* bsum = flags + 2;                  // 256
    int* bpre = bsum + 256;                 // 256
    size_t off_ints = (size_t)((int*)(bpre + 256) - (int*)ws);
    off_ints = (off_ints + 1) & ~(size_t)1;  // 8B align
    uint2* srcW = (uint2*)((int*)ws + off_ints);  // E packed {src, w}
    float* sbuf = A;                        // s[N,16] aliases A (dead by then)

    hipMemsetAsync(ofs, 0, sizeof(int) * (size_t)(N + 1), stream);
    hipMemsetAsync(red, 0, sizeof(float) * 2048 + 2 * sizeof(int), stream);

    int nb = (N + 1023) / 1024;  // scan tiles (<=256 supported)
    k_probe<<<1, 256, 0, stream>>>(W1, eidx, flags);
    k_hist<<<(E + 255) / 256, 256, 0, stream>>>(eidx, flags, ofs, E);
    k_scan1<<<nb, 256, 0, stream>>>(ofs, rowptr, bsum, N);
    k_scan2<<<1, 256, 0, stream>>>(bsum, bpre, rowptr, nb, N);
    k_scan3<<<nb, 256, 0, stream>>>(rowptr, ofs, bpre, N);
    k_scatter<<<(E + 255) / 256, 256, 0, stream>>>(eidx, ew, flags, ofs, srcW, E);
    k_deg<<<(N + 15) / 16, 256, 0, stream>>>(rowptr, srcW, dinv, red + RED_2M, N);

    // layer 1
    k_gemm64<<<(N + 31) / 32, 256, 0, stream>>>(x, 1, W1, flags, A, N);
    k_prop_csr<<<(N + 3) / 4, 256, 0, stream>>>(rowptr, srcW, dinv, A, b1, flags, B, N);
    // layer 2
    k_gemm64<<<(N + 31) / 32, 256, 0, stream>>>(B, 0, W2, flags, A, N);
    k_prop_csr<<<(N + 3) / 4, 256, 0, stream>>>(rowptr, srcW, dinv, A, b2, flags, B, N);

    // assignment + reductions (sbuf aliases A — A is dead after layer-2 prop)
    k_softmax<<<(N + 15) / 16, 256, 0, stream>>>(B, Wp, bp, flags, sbuf, d_out, N);
    k_sty<<<512, 256, 0, stream>>>(sbuf, B, red, N);
    k_ss<<<512, 256, 0, stream>>>(sbuf, red, N);
    k_outadj_csr<<<256, 256, 0, stream>>>(rowptr, srcW, sbuf, red, N);
    k_finalize<<<1, 256, 0, stream>>>(red, d_out, flags, N, N * 16);
}

// Round 6
// 512.423 us; speedup vs baseline: 1.7081x; 1.0926x over previous
//
#include <hip/hip_runtime.h>
#include <hip/hip_bf16.h>

typedef __hip_bfloat16 bf16;
typedef long long i64t;

__device__ __forceinline__ float b2f(bf16 x) { return __bfloat162float(x); }
__device__ __forceinline__ bf16 f2b(float x) { return __float2bfloat16(x); }

// runtime-dtype accessors: isbf/is64 are wave-uniform device flags
__device__ __forceinline__ float loadF(const void* p, int isbf, long long i) {
    return isbf ? b2f(((const bf16*)p)[i]) : ((const float*)p)[i];
}
__device__ __forceinline__ int loadI(const void* p, int is64, long long i) {
    return is64 ? (int)((const i64t*)p)[i] : ((const int*)p)[i];
}
__device__ __forceinline__ void storeO(void* p, int isbf, long long i, float v) {
    if (isbf) ((bf16*)p)[i] = f2b(v);
    else ((float*)p)[i] = v;
}

#define SELU_ALPHA 1.6732632423543772f
#define SELU_SCALE 1.0507009873554805f
__device__ __forceinline__ float selu_f(float x) {
    return SELU_SCALE * (x > 0.f ? x : SELU_ALPHA * (expf(x) - 1.f));
}

__device__ __forceinline__ void atomAddF(float* p, float v) { unsafeAtomicAdd(p, v); }

// red[] layout (floats): [0,1024) sty  [1024,1280) out_adj  [1280,1536) ss
// [1536,1552) ca  [1552,1568) colsum  [1568] two_m
#define RED_STY 0
#define RED_OADJ 1024
#define RED_SS 1280
#define RED_CA 1536
#define RED_CS 1552
#define RED_2M 1568

#define NB_OADJ 1024  // outadj grid; scratch stride 288 = 256 oadj + 16 ca + 16 cs

// ---- dtype probe: flags[0]=floats-are-bf16, flags[1]=indices-are-int64 ----
__global__ void k_probe(const void* W1, const void* eidx, int* flags) {
    __shared__ int sc[2];
    if (threadIdx.x == 0) { sc[0] = 0; sc[1] = 0; }
    __syncthreads();
    const unsigned* w = (const unsigned*)W1;
    int c0 = 0;
    for (int i = threadIdx.x; i < 2048; i += 256) {
        unsigned lo = w[i] & 0xFFFFu;
        unsigned e = (lo >> 7) & 0xFFu;
        if (e == 0u || (e >= 0x60u && e <= 0x8Fu)) c0++;
    }
    const unsigned* iw = (const unsigned*)eidx;
    int c1 = 0;
    for (int i = threadIdx.x; i < 2048; i += 256)
        if (iw[2 * i + 1] == 0u) c1++;
    atomicAdd(&sc[0], c0);
    atomicAdd(&sc[1], c1);
    __syncthreads();
    if (threadIdx.x == 0) {
        flags[0] = sc[0] > 1200 ? 1 : 0;
        flags[1] = sc[1] > 1024 ? 1 : 0;
    }
}

// ---- histogram only: cnt[dst]++ (single atomic per edge) ----
__global__ void k_hist(const void* __restrict__ eidx, const int* __restrict__ flags,
                       int* __restrict__ cnt, int E) {
    int g = blockIdx.x * 256 + threadIdx.x;
    if (g >= E) return;
    int fi = flags[1];
    atomicAdd(&cnt[loadI(eidx, fi, (long long)E + g)], 1);
}

// ---- 3-phase multi-block exclusive scan (tile = 1024 = 256 thr x 4) ----
__global__ void k_scan1(const int* __restrict__ cnt, int* __restrict__ rowptr,
                        int* __restrict__ bsum, int n) {
    __shared__ int part[256];
    int t = threadIdx.x;
    int base = blockIdx.x * 1024 + t * 4;
    int v[4];
    int s = 0;
#pragma unroll
    for (int u = 0; u < 4; u++) {
        int i = base + u;
        v[u] = (i < n) ? cnt[i] : 0;
        s += v[u];
    }
    part[t] = s;
    __syncthreads();
    for (int off = 1; off < 256; off <<= 1) {
        int x = (t >= off) ? part[t - off] : 0;
        __syncthreads();
        part[t] += x;
        __syncthreads();
    }
    int run = t ? part[t - 1] : 0;
#pragma unroll
    for (int u = 0; u < 4; u++) {
        int i = base + u;
        if (i < n) rowptr[i] = run;
        run += v[u];
    }
    if (t == 255) bsum[blockIdx.x] = part[255];
}

__global__ void k_scan2(const int* __restrict__ bsum, int* __restrict__ bpre,
                        int* __restrict__ rowptr, int nb, int n) {
    __shared__ int part[256];
    int t = threadIdx.x;
    part[t] = (t < nb) ? bsum[t] : 0;
    __syncthreads();
    for (int off = 1; off < 256; off <<= 1) {
        int x = (t >= off) ? part[t - off] : 0;
        __syncthreads();
        part[t] += x;
        __syncthreads();
    }
    if (t < nb) bpre[t] = t ? part[t - 1] : 0;
    if (t == 255) rowptr[n] = part[255];
}

__global__ void k_scan3(int* __restrict__ rowptr, int* __restrict__ ofs,
                        const int* __restrict__ bpre, int n) {
    int t = threadIdx.x;
    int add = bpre[blockIdx.x];
    int base = blockIdx.x * 1024 + t * 4;
#pragma unroll
    for (int u = 0; u < 4; u++) {
        int i = base + u;
        if (i < n) {
            int r = rowptr[i] + add;
            rowptr[i] = r;
            ofs[i] = r;
        }
    }
}

// ---- scatter edges into CSR order (by dst), packed {src, w} ----
__global__ void k_scatter(const void* __restrict__ eidx, const void* __restrict__ ew,
                          const int* __restrict__ flags, int* __restrict__ ofs,
                          uint2* __restrict__ srcW, int E) {
    int e = blockIdx.x * 256 + threadIdx.x;
    if (e >= E) return;
    int fb = flags[0], fi = flags[1];
    int s = loadI(eidx, fi, e), d = loadI(eidx, fi, (long long)E + e);
    float w = loadF(ew, fb, e);
    int pos = atomicAdd(&ofs[d], 1);
    srcW[pos] = make_uint2((unsigned)s, __float_as_uint(w));
}

// ---- deg from CSR rows -> dinv; two_m block-reduced. 16 lanes per node ----
__global__ void k_deg(const int* __restrict__ rowptr, const uint2* __restrict__ srcW,
                      float* __restrict__ dinv, float* __restrict__ two_m, int n) {
    int t = threadIdx.x;
    int g = t >> 4, j = t & 15;
    int node = blockIdx.x * 16 + g;
    float wsum = 0.f;
    if (node < n) {
        int i0 = rowptr[node], i1 = rowptr[node + 1];
        for (int i = i0 + j; i < i1; i += 16) wsum += __uint_as_float(srcW[i].y);
        float r = wsum;
        for (int m = 8; m; m >>= 1) r += __shfl_xor(r, m, 16);
        if (j == 0) dinv[node] = rsqrtf(r + 1.f);
    }
    __shared__ float part[4];
    float v = wsum;
    for (int m = 32; m; m >>= 1) v += __shfl_down(v, m, 64);
    int wid = t >> 6, lane = t & 63;
    if (lane == 0) part[wid] = v;
    __syncthreads();
    if (t == 0) atomAddF(two_m, part[0] + part[1] + part[2] + part[3]);
}

// ---- hbf[N,64](bf16) = in[N,64] @ W[64,64]; 32 rows/block, 8 outputs/thread ----
__global__ void k_gemm64(const void* __restrict__ in, int in_tag,
                         const void* __restrict__ W, const int* __restrict__ flags,
                         bf16* __restrict__ out, int n) {
    __shared__ float Wl[4096];
    __shared__ float Rl[2048];
    int t = threadIdx.x;
    int fb = flags[0];
    int inbf = in_tag ? fb : 0;
    for (int idx = t; idx < 4096; idx += 256) Wl[idx] = loadF(W, fb, idx);
    int r0 = blockIdx.x * 32;
    for (int idx = t; idx < 2048; idx += 256) {
        int rl = idx >> 6, k = idx & 63;
        int r = r0 + rl;
        Rl[idx] = (r < n) ? loadF(in, inbf, (long long)r * 64 + k) : 0.f;
    }
    __syncthreads();
    int rl = t >> 6, c = t & 63;
    float acc[8];
#pragma unroll
    for (int u = 0; u < 8; u++) acc[u] = 0.f;
    for (int k = 0; k < 64; k++) {
        float wv = Wl[k * 64 + c];
#pragma unroll
        for (int u = 0; u < 8; u++) acc[u] += Rl[(rl + (u << 2)) * 64 + k] * wv;
    }
#pragma unroll
    for (int u = 0; u < 8; u++) {
        int r = r0 + rl + (u << 2);
        if (r < n) out[(long long)r * 64 + c] = f2b(acc[u]);
    }
}

// ---- CSR propagation + self loop + bias + SELU. wave = node, lane = feature.
//      hin is bf16 (halved gather traffic); output fp32 ----
__global__ void k_prop_csr(const int* __restrict__ rowptr, const uint2* __restrict__ srcW,
                           const float* __restrict__ dinv, const bf16* __restrict__ hin,
                           const void* __restrict__ b, const int* __restrict__ flags,
                           float* __restrict__ out, int n) {
    int t = threadIdx.x;
    int node = blockIdx.x * 4 + (t >> 6);
    if (node >= n) return;
    int f = t & 63;
    int fb = flags[0];
    int i0 = rowptr[node], i1 = rowptr[node + 1];
    float di = dinv[node];
    float accE = 0.f;
    for (int base = i0; base < i1; base += 64) {
        int idx = base + f;
        uint2 p = (idx < i1) ? srcW[idx] : make_uint2(0u, 0u);
        float cw = __uint_as_float(p.y) * dinv[p.x];  // w * dinv[src]
        int m = min(i1 - base, 64);
        for (int j = 0; j < m; j++) {
            int s = __shfl((int)p.x, j, 64);
            float c = __shfl(cw, j, 64);
            accE += c * b2f(hin[(long long)s * 64 + f]);
        }
    }
    float v = di * accE + di * di * b2f(hin[(long long)node * 64 + f]) + loadF(b, fb, f);
    out[(long long)node * 64 + f] = selu_f(v);
}

// ---- logits + softmax -> sbuf (fp32) + out (flagged dtype) ----
__global__ void k_softmax(const float* __restrict__ y, const void* __restrict__ Wp,
                          const void* __restrict__ bp, const int* __restrict__ flags,
                          float* __restrict__ sbuf, void* __restrict__ sout, int n) {
    __shared__ float Wl[1024];
    __shared__ float bl[16];
    __shared__ float yl[1024];
    int t = threadIdx.x;
    int fb = flags[0];
    for (int idx = t; idx < 1024; idx += 256) Wl[idx] = loadF(Wp, fb, idx);
    if (t < 16) bl[t] = loadF(bp, fb, t);
    int g0 = blockIdx.x * 16;
    for (int idx = t; idx < 1024; idx += 256) {
        int nl = idx >> 6, f = idx & 63;
        int g = g0 + nl;
        yl[idx] = (g < n) ? y[(long long)g * 64 + f] : 0.f;
    }
    __syncthreads();
    int nl = t >> 4, k = t & 15;
    int g = g0 + nl;
    float logit = bl[k];
#pragma unroll
    for (int jj = 0; jj < 64; jj++) logit += yl[nl * 64 + jj] * Wl[jj * 16 + k];
    float mx = logit;
    for (int m = 8; m; m >>= 1) mx = fmaxf(mx, __shfl_xor(mx, m, 16));
    float e = expf(logit - mx);
    float sum = e;
    for (int m = 8; m; m >>= 1) sum += __shfl_xor(sum, m, 16);
    float sv = e / sum;
    if (g < n) {
        sbuf[(long long)g * 16 + k] = sv;
        storeO(sout, fb, (long long)g * 16 + k, sv);
    }
}

// ---- fused: sty = S^T y (16x64) and ss = S^T S (16x16) ----
__global__ void k_stats(const float* __restrict__ s, const float* __restrict__ y,
                        float* __restrict__ red, int n) {
    int t = threadIdx.x;
    int k4 = t >> 6, f = t & 63;
    float a0 = 0.f, a1 = 0.f, a2 = 0.f, a3 = 0.f;
    for (int node = blockIdx.x; node < n; node += gridDim.x) {
        float yv = y[(long long)node * 64 + f];
        const float* sp = s + (long long)node * 16;
        a0 += sp[k4] * yv;
        a1 += sp[k4 + 4] * yv;
        a2 += sp[k4 + 8] * yv;
        a3 += sp[k4 + 12] * yv;
    }
    atomAddF(&red[RED_STY + k4 * 64 + f], a0);
    atomAddF(&red[RED_STY + (k4 + 4) * 64 + f], a1);
    atomAddF(&red[RED_STY + (k4 + 8) * 64 + f], a2);
    atomAddF(&red[RED_STY + (k4 + 12) * 64 + f], a3);
    // ss pass: per-block s-range is L1-resident from pass 1
    int i = t >> 4, j = t & 15;
    float acc = 0.f;
    for (int node = blockIdx.x; node < n; node += gridDim.x) {
        const float* sp = s + (long long)node * 16;
        acc += sp[i] * sp[j];
    }
    atomAddF(&red[RED_SS + t], acc);
}

// ---- out_adj via CSR + ca + colsum -> per-block scratch (no hot atomics) ----
__global__ void k_outadj_csr(const int* __restrict__ rowptr, const uint2* __restrict__ srcW,
                             const float* __restrict__ s, float* __restrict__ scratch,
                             int n) {
    __shared__ float lacc[256];
    __shared__ float sca[16];
    __shared__ float scs[16];
    int t = threadIdx.x;
    int g = t >> 4, j = t & 15;
    lacc[t] = 0.f;
    if (t < 16) { sca[t] = 0.f; scs[t] = 0.f; }
    __syncthreads();
    float acc[16];
#pragma unroll
    for (int r = 0; r < 16; r++) acc[r] = 0.f;
    float catot = 0.f, cstot = 0.f;
    for (int node = blockIdx.x * 16 + g; node < n; node += gridDim.x * 16) {
        int i0 = rowptr[node], i1 = rowptr[node + 1];
        float tv = 0.f;
        for (int base = i0; base < i1; base += 16) {
            int idx = base + j;
            uint2 p = (idx < i1) ? srcW[idx] : make_uint2(0u, 0u);
            float wl = __uint_as_float(p.y);
            int m = min(i1 - base, 16);
            for (int r = 0; r < m; r++) {
                int sidx = __shfl((int)p.x, r, 16);
                float w = __shfl(wl, r, 16);
                tv += w * s[(long long)sidx * 16 + j];
            }
        }
        float sj = s[(long long)node * 16 + j];
        catot += tv;
        cstot += sj;
#pragma unroll
        for (int r = 0; r < 16; r++) acc[r] += __shfl(tv, r, 16) * sj;
    }
#pragma unroll
    for (int r = 0; r < 16; r++) atomicAdd(&lacc[r * 16 + j], acc[r]);
    atomicAdd(&sca[j], catot);
    atomicAdd(&scs[j], cstot);
    __syncthreads();
    float* dstp = scratch + (long long)blockIdx.x * 288;
    dstp[t] = lacc[t];
    if (t < 16) {
        dstp[256 + t] = sca[t];
        dstp[272 + t] = scs[t];
    }
}

// ---- reduce outadj scratch: 288 blocks x 64 threads ----
__global__ void k_oadj_reduce(const float* __restrict__ scratch, float* __restrict__ red) {
    int o = blockIdx.x;
    int t = threadIdx.x;
    float sum = 0.f;
    for (int b = t; b < NB_OADJ; b += 64) sum += scratch[(long long)b * 288 + o];
    for (int m = 32; m; m >>= 1) sum += __shfl_down(sum, m, 64);
    if (t == 0) {
        if (o < 256) red[RED_OADJ + o] = sum;
        else if (o < 272) red[RED_CA + o - 256] = sum;
        else red[RED_CS + o - 272] = sum;
    }
}

__device__ float blockReduceSum256(float v) {
    __shared__ float part[4];
    for (int m = 32; m; m >>= 1) v += __shfl_down(v, m, 64);
    int wid = threadIdx.x >> 6, lane = threadIdx.x & 63;
    if (lane == 0) part[wid] = v;
    __syncthreads();
    v = part[0] + part[1] + part[2] + part[3];
    __syncthreads();
    return v;
}

// ---- single-block finalize: losses + adj postprocess + out features ----
__global__ void k_finalize(const float* __restrict__ red, void* __restrict__ out,
                           const int* __restrict__ flags, int n_nodes, int base) {
    int t = threadIdx.x;
    int fb = flags[0];
    for (int idx = t; idx < 1024; idx += 256)
        storeO(out, fb, base + idx, selu_f(red[RED_STY + idx]));
    int i = t >> 4, j = t & 15;
    float ss_t = red[RED_SS + t];
    float oadj_t = red[RED_OADJ + t];
    float two_m = red[RED_2M];

    float norm_ss = sqrtf(blockReduceSum256(ss_t * ss_t));
    float diff = ss_t / norm_ss - ((i == j) ? 0.25f : 0.f);
    float ortho = sqrtf(blockReduceSum256(diff * diff));
    float trace = blockReduceSum256((i == j) ? oadj_t : 0.f);
    float ca_t = (t < 16) ? red[RED_CA + t] : 0.f;
    float cad = blockReduceSum256(ca_t * ca_t);
    float spectral = -(trace - cad / two_m) / two_m;
    float cs_t = (t < 16) ? red[RED_CS + t] : 0.f;
    float cluster = sqrtf(blockReduceSum256(cs_t * cs_t)) / (float)n_nodes * 4.f - 1.f;

    float a = (i == j) ? 0.f : oadj_t;
    float rs = a;
    for (int m = 8; m; m >>= 1) rs += __shfl_xor(rs, m, 16);
    __shared__ float ddl[16];
    float dd_i = sqrtf(rs) + 1e-15f;
    if (j == 0) ddl[i] = dd_i;
    __syncthreads();
    float aout = a / (dd_i * ddl[j]);
    storeO(out, fb, base + 1024 + t, aout);
    if (t == 0) {
        storeO(out, fb, base + 1280, spectral);
        storeO(out, fb, base + 1281, ortho);
        storeO(out, fb, base + 1282, cluster);
    }
}

extern "C" void kernel_launch(void* const* d_in, const int* in_sizes, int n_in,
                              void* d_out, int out_size, void* d_ws, size_t ws_size,
                              hipStream_t stream) {
    const void* x = d_in[0];
    const void* eidx = d_in[1];
    const void* ew = d_in[2];
    const void* W1 = d_in[3];
    const void* b1 = d_in[4];
    const void* W2 = d_in[5];
    const void* b2 = d_in[6];
    const void* Wp = d_in[7];
    const void* bp = d_in[8];

    const int N = in_sizes[0] / 64;
    const int E = in_sizes[2];

    float* ws = (float*)d_ws;
    float* B = ws;                          // N*64 fp32 (prop out / gemm in)
    float* hbf_f = B + (size_t)N * 64;      // N*32 floats = N*64 bf16 (gemm out)
    bf16* hbf = (bf16*)hbf_f;
    float* sbuf = hbf_f;                    // s[N,16] fp32, aliases hbf (dead then)
    float* dinv = hbf_f + (size_t)N * 32;   // N
    int* rowptr = (int*)(dinv + N);         // N+1
    int* ofs = rowptr + (N + 1);            // N+1 (hist counts, then bump ptrs)
    float* red = (float*)(ofs + (N + 1));   // 2048
    int* flags = (int*)(red + 2048);        // 2
    int* bsum = flags + 2;                  // 256
    int* bpre = bsum + 256;                 // 256
    size_t off_ints = (size_t)((int*)(bpre + 256) - (int*)ws);
    off_ints = (off_ints + 1) & ~(size_t)1;  // 8B align
    uint2* srcW = (uint2*)((int*)ws + off_ints);   // E packed {src, w}
    float* scratch = (float*)(srcW + E);           // NB_OADJ*288

    hipMemsetAsync(ofs, 0, sizeof(int) * (size_t)(N + 1), stream);
    hipMemsetAsync(red, 0, sizeof(float) * 2048 + 2 * sizeof(int), stream);

    int nb = (N + 1023) / 1024;  // scan tiles (<=256 supported)
    k_probe<<<1, 256, 0, stream>>>(W1, eidx, flags);
    k_hist<<<(E + 255) / 256, 256, 0, stream>>>(eidx, flags, ofs, E);
    k_scan1<<<nb, 256, 0, stream>>>(ofs, rowptr, bsum, N);
    k_scan2<<<1, 256, 0, stream>>>(bsum, bpre, rowptr, nb, N);
    k_scan3<<<nb, 256, 0, stream>>>(rowptr, ofs, bpre, N);
    k_scatter<<<(E + 255) / 256, 256, 0, stream>>>(eidx, ew, flags, ofs, srcW, E);
    k_deg<<<(N + 15) / 16, 256, 0, stream>>>(rowptr, srcW, dinv, red + RED_2M, N);

    // layer 1: gemm -> bf16 staging -> prop -> fp32 B
    k_gemm64<<<(N + 31) / 32, 256, 0, stream>>>(x, 1, W1, flags, hbf, N);
    k_prop_csr<<<(N + 3) / 4, 256, 0, stream>>>(rowptr, srcW, dinv, hbf, b1, flags, B, N);
    // layer 2
    k_gemm64<<<(N + 31) / 32, 256, 0, stream>>>(B, 0, W2, flags, hbf, N);
    k_prop_csr<<<(N + 3) / 4, 256, 0, stream>>>(rowptr, srcW, dinv, hbf, b2, flags, B, N);

    // assignment + reductions (sbuf aliases hbf — dead after layer-2 prop)
    k_softmax<<<(N + 15) / 16, 256, 0, stream>>>(B, Wp, bp, flags, sbuf, d_out, N);
    k_stats<<<512, 256, 0, stream>>>(sbuf, B, red, N);
    k_outadj_csr<<<NB_OADJ, 256, 0, stream>>>(rowptr, srcW, sbuf, scratch, N);
    k_oadj_reduce<<<288, 64, 0, stream>>>(scratch, red);
    k_finalize<<<1, 256, 0, stream>>>(red, d_out, flags, N, N * 16);
}